// Round 9
// baseline (3148.702 us; speedup 1.0000x reference)
//
#include <hip/hip_runtime.h>
#include <hip/hip_bf16.h>
#include <math.h>

#define L_IN 1549
#define S_OUT 512

typedef __hip_bfloat16 bf16;
typedef __attribute__((ext_vector_type(8))) short bfrag;    // 8 bf16 (4 VGPRs)
typedef __attribute__((ext_vector_type(4))) float f32x4;    // MFMA accumulator

__device__ __forceinline__ float bfbits2f(unsigned short u) {
    union { unsigned int i; float f; } x;
    x.i = ((unsigned int)u) << 16;
    return x.f;
}
__device__ __forceinline__ unsigned short f2bfbits(float f) {
    union { float f; unsigned int i; } x; x.f = f;
    unsigned int lsb = (x.i >> 16) & 1;
    return (unsigned short)((x.i + 0x7fff + lsb) >> 16);
}

// fast activations: single v_exp_f32 / v_rcp_f32 (<=1 ulp HW ops).
// limits are exact: e=inf -> rcp(inf)=0 (no NR step, so no inf*0 NaN).
__device__ __forceinline__ float fast_sig(float x) {
    float e = __builtin_amdgcn_exp2f(-1.442695041f * x);   // exp(-x)
    return __builtin_amdgcn_rcpf(1.f + e);
}
__device__ __forceinline__ float fast_tanh(float x) {
    float e = __builtin_amdgcn_exp2f(2.885390082f * x);    // exp(2x)
    return 1.f - 2.f * __builtin_amdgcn_rcpf(1.f + e);
}

// bf16-pair dot product: c + lo(w)*lo(h) + hi(w)*hi(h)
#if __has_builtin(__builtin_amdgcn_fdot2_f32_bf16)
typedef __attribute__((ext_vector_type(2))) __bf16 v2bf;
__device__ __forceinline__ float dot2bf(unsigned int w, unsigned int h, float c) {
    union { unsigned int u; v2bf v; } a, b;
    a.u = w; b.u = h;
    return __builtin_amdgcn_fdot2_f32_bf16(a.v, b.v, c, false);
}
#else
__device__ __forceinline__ float dot2bf(unsigned int w, unsigned int h, float c) {
    union { unsigned int i; float f; } w0, w1, h0, h1;
    w0.i = w << 16; w1.i = w & 0xffff0000u;
    h0.i = h << 16; h1.i = h & 0xffff0000u;
    return c + w0.f * h0.f + w1.f * h1.f;
}
#endif

// ---------------------------------------------------------------------------
// conv1d(k=16,pad=1) + BN + ReLU + maxpool(3,3) + transpose -> h0 (B,512,32) bf16
// Weight row hoisted out of the pool-tap loop (3x fewer global loads).
// ---------------------------------------------------------------------------
__global__ __launch_bounds__(256) void conv_bn_pool(
    const float* __restrict__ x, const float* __restrict__ w,
    const float* __restrict__ cb, const float* __restrict__ gamma,
    const float* __restrict__ beta, const float* __restrict__ mean,
    const float* __restrict__ var, bf16* __restrict__ h0)
{
    int b  = blockIdx.y;
    int sg = blockIdx.x;
    __shared__ float xs[32][40];
    int tid = threadIdx.x;
    int base = sg * 24;
    for (int i = tid; i < 32 * 40; i += 256) {
        int ci = i / 40, dl = i % 40;
        int l = base - 1 + dl;
        xs[ci][dl] = (l >= 0 && l < L_IN) ? x[(size_t)(b * 32 + ci) * L_IN + l] : 0.f;
    }
    __syncthreads();
    int c = tid & 31, sl = tid >> 5;
    float scale = gamma[c] * rsqrtf(var[c] + 1e-5f);
    float shift = beta[c] - mean[c] * scale;
    float bias = cb[c];
    float acc0 = bias, acc1 = bias, acc2 = bias;
    int off0 = 3 * sl;
    for (int ci = 0; ci < 32; ++ci) {
        const float* wrp = w + (size_t)(c * 32 + ci) * 16;
        float4 w0 = *(const float4*)(wrp);
        float4 w1 = *(const float4*)(wrp + 4);
        float4 w2 = *(const float4*)(wrp + 8);
        float4 w3 = *(const float4*)(wrp + 12);
        float wk[16] = {w0.x, w0.y, w0.z, w0.w, w1.x, w1.y, w1.z, w1.w,
                        w2.x, w2.y, w2.z, w2.w, w3.x, w3.y, w3.z, w3.w};
        const float* xr = &xs[ci][off0];
        #pragma unroll
        for (int kk = 0; kk < 16; ++kk) {
            float xv0 = xr[kk];
            float xv1 = xr[kk + 1];
            float xv2 = xr[kk + 2];
            acc0 += xv0 * wk[kk];
            acc1 += xv1 * wk[kk];
            acc2 += xv2 * wk[kk];
        }
    }
    float y0 = fmaxf(acc0 * scale + shift, 0.f);
    float y1 = fmaxf(acc1 * scale + shift, 0.f);
    float y2 = fmaxf(acc2 * scale + shift, 0.f);
    float best = fmaxf(fmaxf(y0, y1), y2);
    int s = sg * 8 + sl;
    h0[((size_t)b * S_OUT + s) * 32 + c] = __float2bfloat16(best);
}

// ---------------------------------------------------------------------------
// Pack 4 x W_hh (1024,256) fp32 for lstm_reg in ONE launch (blockIdx.y = set).
// 1024-thread column map: thread g (0..1023) owns gate column g.
// For gate col g, k-pair kp: pair = pack(W[g*256+2kp], W[g*256+2kp+1]).
//  R (reg,   kp   0..99):  out[kp*1024 + g]
//  L (LDS,   kp 100..113): out[102400 + (kp-100)*1024 + g]
//  S (stream,kp 114..127): out[116736 + (kp-114)*1024 + g]
// ---------------------------------------------------------------------------
__global__ void pack_lstm4(
    const float* __restrict__ W0, const float* __restrict__ W1,
    const float* __restrict__ W2, const float* __restrict__ W3,
    unsigned int* __restrict__ outbase)
{
    int set = blockIdx.y;
    const float* W = (set == 0) ? W0 : (set == 1) ? W1 : (set == 2) ? W2 : W3;
    unsigned int* out = outbase + (size_t)set * 131072;
    int i = blockIdx.x * 256 + threadIdx.x;   // 0..131071
    int kp, g;
    if (i < 102400) {
        kp = i >> 10; g = i & 1023;
    } else if (i < 116736) {
        int j = i - 102400;
        kp = 100 + (j >> 10); g = j & 1023;
    } else {
        int j = i - 116736;
        kp = 114 + (j >> 10); g = j & 1023;
    }
    unsigned int lo = f2bfbits(W[(size_t)g * 256 + 2 * kp]);
    unsigned int hi = f2bfbits(W[(size_t)g * 256 + 2 * kp + 1]);
    out[i] = lo | (hi << 16);
}

// ---------------------------------------------------------------------------
// Pack the 7 GEMM B matrices (fp32 -> bf16, RNE) ONCE:
//  [0]       W_ih0f (1024x32)   32768
//  [32768]   W_ih0b (1024x32)   32768
//  [65536]   W_ih1f (1024x512)  524288
//  [589824]  W_ih1b (1024x512)  524288
//  [1114112] Wq     (512x512)   262144
//  [1376256] Wk     (512x512)   262144
//  [1638400] Wv     (512x512)   262144   total 1,900,544 elems
// ---------------------------------------------------------------------------
__global__ __launch_bounds__(256) void pack_b7(
    const float* __restrict__ A0, const float* __restrict__ A1,
    const float* __restrict__ A2, const float* __restrict__ A3,
    const float* __restrict__ A4, const float* __restrict__ A5,
    const float* __restrict__ A6, unsigned short* __restrict__ out)
{
    int i = blockIdx.x * 256 + threadIdx.x;
    const float* src; int j;
    if      (i <   32768) { src = A0; j = i; }
    else if (i <   65536) { src = A1; j = i - 32768; }
    else if (i <  589824) { src = A2; j = i - 65536; }
    else if (i < 1114112) { src = A3; j = i - 589824; }
    else if (i < 1376256) { src = A4; j = i - 1114112; }
    else if (i < 1638400) { src = A5; j = i - 1376256; }
    else if (i < 1900544) { src = A6; j = i - 1638400; }
    else return;
    out[i] = f2bfbits(src[j]);
}

// ---------------------------------------------------------------------------
// MFMA bf16 GEMM:  C = A @ B^T + bias.  A (M,K) bf16, B (N,K) bf16 (pre-packed
// by pack_b7).  128x128 tile, BK=32, 4 waves x 4x4 16x16x32 MFMAs.
// LDS tiles padded to stride 40; XCD-aware 1D grid swizzle.
// ---------------------------------------------------------------------------
#define LDA 40
__global__ __launch_bounds__(256) void gemm_mfma(
    const bf16* __restrict__ A,
    const bf16* __restrict__ Bm0, const bf16* __restrict__ Bm1, const bf16* __restrict__ Bm2,
    const float* __restrict__ bs0, const float* __restrict__ bs1, const float* __restrict__ bs2,
    bf16* __restrict__ Cm0, bf16* __restrict__ Cm1, bf16* __restrict__ Cm2,
    int M, int N, int K)
{
    int nbn = N >> 7;                    // N/128
    int nbm = M >> 7;                    // M/128
    int lid = blockIdx.x;
    int xcd = lid & 7;
    int slot = lid >> 3;
    int bn = slot % nbn;
    int pair = xcd + 8 * (slot / nbn);   // (bm, z) pair index
    int bm = pair % nbm;
    int z  = pair / nbm;

    const bf16* B = (z == 0) ? Bm0 : ((z == 1) ? Bm1 : Bm2);
    const float* bias = (z == 0) ? bs0 : ((z == 1) ? bs1 : bs2);
    bf16* C = (z == 0) ? Cm0 : ((z == 1) ? Cm1 : Cm2);

    __shared__ bf16 As[128 * LDA];
    __shared__ bf16 Bs[128 * LDA];

    int tid = threadIdx.x;
    int lane = tid & 63;
    int wave = tid >> 6;
    int wm = (wave >> 1) * 64;
    int wn = (wave & 1) * 64;

    int sr = tid >> 2;
    int sc = (tid & 3) * 8;
    const bf16* Ag = A + (size_t)(bm * 128 + sr) * K + sc;
    const bf16* Bg = B + (size_t)(bn * 128 + sr) * K + sc;

    int fm = lane & 15;
    int fk = (lane >> 4) * 8;

    f32x4 acc[4][4];
    #pragma unroll
    for (int i = 0; i < 4; ++i)
        #pragma unroll
        for (int j = 0; j < 4; ++j) acc[i][j] = (f32x4)(0.f);

    for (int k0 = 0; k0 < K; k0 += 32) {
        float4 a0 = *(const float4*)(Ag + k0);
        float4 a1 = *(const float4*)(Ag + (size_t)64 * K + k0);
        float4 b0 = *(const float4*)(Bg + k0);
        float4 b1 = *(const float4*)(Bg + (size_t)64 * K + k0);
        __syncthreads();
        *(float4*)(As + sr * LDA + sc)        = a0;
        *(float4*)(As + (sr + 64) * LDA + sc) = a1;
        *(float4*)(Bs + sr * LDA + sc)        = b0;
        *(float4*)(Bs + (sr + 64) * LDA + sc) = b1;
        __syncthreads();

        bfrag af[4], bfr[4];
        #pragma unroll
        for (int i = 0; i < 4; ++i)
            af[i] = *(const bfrag*)(As + (wm + i * 16 + fm) * LDA + fk);
        #pragma unroll
        for (int j = 0; j < 4; ++j)
            bfr[j] = *(const bfrag*)(Bs + (wn + j * 16 + fm) * LDA + fk);
        #pragma unroll
        for (int i = 0; i < 4; ++i)
            #pragma unroll
            for (int j = 0; j < 4; ++j)
                acc[i][j] = __builtin_amdgcn_mfma_f32_16x16x32_bf16(
                    af[i], bfr[j], acc[i][j], 0, 0, 0);
    }

    int rbase = (lane >> 4) * 4;
    #pragma unroll
    for (int j = 0; j < 4; ++j) {
        int n = bn * 128 + wn + j * 16 + (lane & 15);
        float bv = bias[n];
        #pragma unroll
        for (int i = 0; i < 4; ++i) {
            #pragma unroll
            for (int r = 0; r < 4; ++r) {
                int m = bm * 128 + wm + i * 16 + rbase + r;
                C[(size_t)m * N + n] = __float2bfloat16(acc[i][j][r] + bv);
            }
        }
    }
}

// ---------------------------------------------------------------------------
// LSTM recurrence, 1024-thread variant.
// One block per (batch,dir), 1024 thr: thread g owns ONE gate column g.
// Rationale: 128 blocks on 256 CUs leaves 2 waves/SIMD (Occupancy 12%) --
// the step's dominant cost was unhidden LDS/dep latency.  1024 thr doubles
// waves/SIMD (2->4) on the active CUs at identical aggregate VALU issue:
// per-thread work halves (128 dot2, 2 interleaved 64-deep chains).
// kp 0..99 in regs (wr[100]), 100..113 in LDS, 114..127 streamed from L2.
// h broadcast (uniform ds_read_b128), gsh exchange, 2 barriers/step, out
// store post-barrier -- all phases identical to the verified 820us kernel.
// ---------------------------------------------------------------------------
__global__ __launch_bounds__(1024, 1) void lstm_reg(
    const bf16* __restrict__ xg_f, const bf16* __restrict__ xg_b,
    const unsigned int* __restrict__ Wl, bf16* __restrict__ out)
{
    int u = blockIdx.x;          // 0..127
    int b = u & 63, dir = u >> 6;
    const unsigned int* W = Wl + (size_t)dir * 131072;
    const bf16* xg = dir ? xg_b : xg_f;
    int t = threadIdx.x;         // 0..1023 = gate column

    __shared__ unsigned int lw[14336];                    // 56 KB weight slice
    __shared__ __align__(16) unsigned int hsb[2][128];    // h bf16 pairs, dbuf
    __shared__ float gsh[1024];                           // gates

    unsigned int wr[100];
    #pragma unroll
    for (int j = 0; j < 100; ++j) wr[j] = W[j * 1024 + t];
    for (int i = t; i < 14336; i += 1024) lw[i] = W[102400 + i];
    if (t < 128) { hsb[0][t] = 0u; }
    float cst = 0.f;             // cell state of position t (t < 256)
    __syncthreads();

    const unsigned int* Wst = W + 116736;
    int par = 0;
    unsigned short hb = 0;
    size_t oaddr = 0;
    bool have_out = false;

    for (int step = 0; step < 512; ++step) {
        int ts = dir ? (511 - step) : step;

        // issue stream + xg loads first (latency overlapped with reg MACs)
        unsigned int sw[14];
        #pragma unroll
        for (int s = 0; s < 14; ++s)
            sw[s] = Wst[s * 1024 + t];
        unsigned short xvs =
            *(const unsigned short*)(xg + ((size_t)b * 512 + ts) * 1024 + t);

        const unsigned int* hs = hsb[par];
        float a0 = 0.f, e0 = 0.f;     // 2 interleaved chains (dep-latency)
        #pragma unroll
        for (int q = 0; q < 32; ++q) {
            uint4 hv = *(const uint4*)&hs[q * 4];
            #pragma unroll
            for (int r = 0; r < 4; ++r) {
                int kp = q * 4 + r;
                unsigned int h2 = (&hv.x)[r];
                float& d = (r & 1) ? e0 : a0;
                if (kp < 100) {
                    d = dot2bf(wr[kp], h2, d);
                } else if (kp < 114) {
                    d = dot2bf(lw[(kp - 100) * 1024 + t], h2, d);
                } else {
                    d = dot2bf(sw[kp - 114], h2, d);
                }
            }
        }
        a0 += e0;
        a0 += bfbits2f(xvs);

        gsh[t] = a0;
        __syncthreads();

        if (t < 256) {
            float gi = gsh[t], gf = gsh[256 + t], gg = gsh[512 + t], go = gsh[768 + t];
            float si = fast_sig(gi);
            float sf = fast_sig(gf);
            float so = fast_sig(go);
            cst = sf * cst + si * fast_tanh(gg);
            float h = so * fast_tanh(cst);
            hb = f2bfbits(h);
            ((unsigned short*)hsb[par ^ 1])[t] = hb;
            oaddr = ((size_t)b * 512 + ts) * 512 + dir * 256 + t;
            have_out = true;
        }
        __syncthreads();
        // out store off the critical path: drains at the NEXT step's barrier
        if (have_out) {
            *(unsigned short*)(out + oaddr) = hb;
            have_out = false;
        }
        par ^= 1;
    }
}

// ---------------------------------------------------------------------------
// V transpose: vt[b][n][s] = v[b][s][n]   (64x64 tiles via LDS)
// ---------------------------------------------------------------------------
__global__ __launch_bounds__(256) void vt_transpose(
    const bf16* __restrict__ v, bf16* __restrict__ vt)
{
    __shared__ unsigned short tile[64 * 73];
    int b = blockIdx.z;
    int s0 = blockIdx.x * 64, n0 = blockIdx.y * 64;
    int tid = threadIdx.x;
    #pragma unroll
    for (int u = 0; u < 2; ++u) {
        int idx = tid + u * 256;
        int si = idx >> 3, nj = (idx & 7) << 3;
        bfrag val = *(const bfrag*)(v + ((size_t)(b * 512 + s0 + si)) * 512 + n0 + nj);
        #pragma unroll
        for (int jj = 0; jj < 8; ++jj)
            tile[(nj + jj) * 73 + si] = ((unsigned short*)&val)[jj];
    }
    __syncthreads();
    #pragma unroll
    for (int u = 0; u < 2; ++u) {
        int idx = tid + u * 256;
        int ni = idx >> 3, sj = (idx & 7) << 3;
        unsigned short outv[8];
        #pragma unroll
        for (int jj = 0; jj < 8; ++jj)
            outv[jj] = tile[ni * 73 + sj + jj];
        *(float4*)(vt + (size_t)b * 262144 + (size_t)(n0 + ni) * 512 + s0 + sj) =
            *(float4*)outv;
    }
}

// ---------------------------------------------------------------------------
// MFMA attention (fast exp2/log2 head-softmax).
// XCD-aware block swizzle: all 16 s0-tiles of one batch land on the SAME XCD
// so each XCD's L2 fetches each batch's K+Vt (1 MB) exactly once.
// ---------------------------------------------------------------------------
__global__ __launch_bounds__(256, 2) void attention_mfma(
    const bf16* __restrict__ q, const bf16* __restrict__ k,
    const bf16* __restrict__ vt, bf16* r)
{
    int n_ = blockIdx.x;                 // 0..1023
    int xcd = n_ & 7;
    int slot = n_ >> 3;                  // 0..127 within XCD
    int b = xcd + ((slot >> 4) << 3);    // batches b = xcd (mod 8) on this XCD
    int s0 = (slot & 15) * 32;
    int tid = threadIdx.x;
    int wave = tid >> 6;
    int sw = wave & 1, dh = wave >> 1;
    int lane = tid & 63;
    int L15 = lane & 15, quad = lane >> 4;

    const bf16* qrow = q + ((size_t)(b * 512 + s0 + sw * 16 + L15)) * 512;
    bfrag qf[8][2];
    #pragma unroll
    for (int h = 0; h < 8; ++h) {
        qf[h][0] = *(const bfrag*)(qrow + h * 64 + quad * 8);
        qf[h][1] = *(const bfrag*)(qrow + h * 64 + 32 + quad * 8);
    }

    f32x4 ctxa[8][2];
    #pragma unroll
    for (int h = 0; h < 8; ++h) {
        ctxa[h][0] = (f32x4)(0.f);
        ctxa[h][1] = (f32x4)(0.f);
    }

    int tperm = ((L15 >> 2) << 3) + (L15 & 3);
    const bf16* kbase = k + (size_t)(b * 512) * 512;
    const bf16* vbase = vt + (size_t)b * 262144;

    for (int tc = 0; tc < 512; tc += 32) {
        f32x4 sa[8][2];
        #pragma unroll
        for (int h = 0; h < 8; ++h) {
            #pragma unroll
            for (int tile = 0; tile < 2; ++tile) {
                const bf16* krow = kbase
                    + (size_t)(tc + tile * 4 + tperm) * 512 + h * 64 + quad * 8;
                bfrag a0 = *(const bfrag*)(krow);
                bfrag a1 = *(const bfrag*)(krow + 32);
                f32x4 acc = __builtin_amdgcn_mfma_f32_16x16x32_bf16(
                    a0, qf[h][0], (f32x4)(0.f), 0, 0, 0);
                acc = __builtin_amdgcn_mfma_f32_16x16x32_bf16(
                    a1, qf[h][1], acc, 0, 0, 0);
                sa[h][tile] = acc;
            }
        }
        bfrag pf[8];
        #pragma unroll
        for (int tile = 0; tile < 2; ++tile) {
            #pragma unroll
            for (int rr = 0; rr < 4; ++rr) {
                float sc[8];
                float m = -1e30f;
                #pragma unroll
                for (int h = 0; h < 8; ++h) {
                    sc[h] = sa[h][tile][rr] * 0.125f;
                    m = fmaxf(m, sc[h]);
                }
                float sum = 0.f;
                #pragma unroll
                for (int h = 0; h < 8; ++h)
                    sum += __builtin_amdgcn_exp2f((sc[h] - m) * 1.442695041f);
                float lse = m + 0.6931471806f * __builtin_amdgcn_logf(sum);
                #pragma unroll
                for (int h = 0; h < 8; ++h)
                    ((unsigned short*)&pf[h])[tile * 4 + rr] = f2bfbits(sc[h] - lse);
            }
        }
        #pragma unroll
        for (int h = 0; h < 8; ++h) {
            #pragma unroll
            for (int dt = 0; dt < 2; ++dt) {
                int n = h * 64 + dh * 32 + dt * 16 + L15;
                bfrag vf = *(const bfrag*)(vbase + (size_t)n * 512 + tc + quad * 8);
                ctxa[h][dt] = __builtin_amdgcn_mfma_f32_16x16x32_bf16(
                    pf[h], vf, ctxa[h][dt], 0, 0, 0);
            }
        }
    }
    #pragma unroll
    for (int h = 0; h < 8; ++h) {
        #pragma unroll
        for (int dt = 0; dt < 2; ++dt) {
            int n = h * 64 + dh * 32 + dt * 16 + L15;
            #pragma unroll
            for (int rr = 0; rr < 4; ++rr) {
                size_t addr =
                    ((size_t)(b * 512 + s0 + sw * 16 + quad * 4 + rr)) * 512 + n;
                float o = __bfloat162float(r[addr]);
                r[addr] = __float2bfloat16(o + ctxa[h][dt][rr]);
            }
        }
    }
}

// ---------------------------------------------------------------------------
// LayerNorm(last dim) -> mean over S -> fc, barrier-free.
// One WAVE per (b,s) row: grid (64 sgroups, 64 b) x 512 thr (8 waves/block).
// Full row reduction via __shfl_xor butterflies (no LDS, no __syncthreads).
// var = E[x^2] - mu^2.
// ---------------------------------------------------------------------------
__global__ __launch_bounds__(512) void ln_pool_fc(
    const bf16* __restrict__ r, const float* __restrict__ g, const float* __restrict__ bt,
    const float* __restrict__ fcw, const float* __restrict__ fcb, float* __restrict__ out)
{
    int b = blockIdx.y;
    int s = blockIdx.x * 8 + (threadIdx.x >> 6);
    int lane = threadIdx.x & 63;
    int n0 = lane * 8;

    // per-lane column constants (columns fixed per lane)
    float gf[8];
    float btf = 0.f;
    #pragma unroll
    for (int j = 0; j < 8; ++j) {
        float fw = fcw[n0 + j];
        gf[j] = g[n0 + j] * fw;
        btf += bt[n0 + j] * fw;
    }

    bfrag rv = *(const bfrag*)(r + ((size_t)(b * 512 + s)) * 512 + n0);
    float v[8];
    float s1 = 0.f, s2 = 0.f;
    #pragma unroll
    for (int j = 0; j < 8; ++j) {
        v[j] = bfbits2f(((const unsigned short*)&rv)[j]);
        s1 += v[j];
        s2 += v[j] * v[j];
    }
    #pragma unroll
    for (int off = 32; off > 0; off >>= 1) {
        s1 += __shfl_xor(s1, off);
        s2 += __shfl_xor(s2, off);
    }
    float mu = s1 * (1.f / 512.f);
    float var = s2 * (1.f / 512.f) - mu * mu;
    float rs = rsqrtf(var + 1e-5f);

    float d = 0.f;
    #pragma unroll
    for (int j = 0; j < 8; ++j) d += (v[j] - mu) * gf[j];
    #pragma unroll
    for (int off = 32; off > 0; off >>= 1) {
        d += __shfl_down(d, off);
        btf += __shfl_down(btf, off);
    }
    if (lane == 0) {
        float val = d * rs * (1.f / 512.f);
        if (s == 0) val += btf + fcb[0];
        atomicAdd(out + b, val);
    }
}

// ---------------------------------------------------------------------------
// Workspace layout (< 200 MiB):
//   [0,64M)        xgf bf16            -> later q,k
//   [64,128M)      xgb bf16            -> later v
//   [128,160M)     out0 bf16           -> later vt (V transposed)
//   [160,192M)     out1 bf16 (attention in-place)
//   [192,194M)     h0 bf16
//   [194,196M)     wl0/wl1 (4 contiguous sets x 131,072 dwords)
//   [196,~199.6M)  wpk bf16 (7 packed B matrices, 1,900,544 elems)
// ---------------------------------------------------------------------------
extern "C" void kernel_launch(void* const* d_in, const int* in_sizes, int n_in,
                              void* d_out, int out_size, void* d_ws, size_t ws_size,
                              hipStream_t stream)
{
    (void)in_sizes; (void)n_in; (void)ws_size;
    const float* x      = (const float*)d_in[0];
    const float* conv_w = (const float*)d_in[1];
    const float* conv_b = (const float*)d_in[2];
    const float* bn_g   = (const float*)d_in[3];
    const float* bn_b   = (const float*)d_in[4];
    const float* bn_m   = (const float*)d_in[5];
    const float* bn_v   = (const float*)d_in[6];
    const float* W_ih0f = (const float*)d_in[7];
    const float* W_hh0f = (const float*)d_in[8];
    const float* b0f    = (const float*)d_in[9];
    const float* W_ih0b = (const float*)d_in[10];
    const float* W_hh0b = (const float*)d_in[11];
    const float* b0b    = (const float*)d_in[12];
    const float* W_ih1f = (const float*)d_in[13];
    const float* W_hh1f = (const float*)d_in[14];
    const float* b1f    = (const float*)d_in[15];
    const float* W_ih1b = (const float*)d_in[16];
    const float* W_hh1b = (const float*)d_in[17];
    const float* b1b    = (const float*)d_in[18];
    const float* Wq = (const float*)d_in[19];
    const float* bq = (const float*)d_in[20];
    const float* Wk = (const float*)d_in[21];
    const float* bk = (const float*)d_in[22];
    const float* Wv = (const float*)d_in[23];
    const float* bv = (const float*)d_in[24];
    const float* ln_g = (const float*)d_in[25];
    const float* ln_b = (const float*)d_in[26];
    const float* fc_w = (const float*)d_in[27];
    const float* fc_b = (const float*)d_in[28];
    float* out = (float*)d_out;

    char* ws = (char*)d_ws;
    bf16* xgf  = (bf16*)ws;                               // 33,554,432
    bf16* xgb  = xgf + 33554432;                          // 33,554,432
    bf16* out0 = (bf16*)(ws + 134217728);                 // 16,777,216
    bf16* out1 = (bf16*)(ws + 167772160);                 // 16,777,216
    bf16* h0   = (bf16*)(ws + 201326592);                 // 1,048,576
    unsigned int* wl0 = (unsigned int*)(ws + 203423744);  // 262,144 dwords
    unsigned int* wl1 = wl0 + 262144;                     // 262,144 dwords
    bf16* wpk  = (bf16*)(ws + 205520896);                 // 1,900,544 bf16
    // q,k,v alias the (dead after lstm1) xg region; vt aliases dead out0
    bf16* qb = xgf;
    bf16* kb = xgf + 16777216;
    bf16* vb = xgb;
    bf16* vtb = out0;

    hipMemsetAsync(d_out, 0, (size_t)out_size * sizeof(float), stream);

    pack_lstm4<<<dim3(512, 4), 256, 0, stream>>>(
        W_hh0f, W_hh0b, W_hh1f, W_hh1b, wl0);

    pack_b7<<<7424, 256, 0, stream>>>(
        W_ih0f, W_ih0b, W_ih1f, W_ih1b, Wq, Wk, Wv, (unsigned short*)wpk);

    conv_bn_pool<<<dim3(64, 64), 256, 0, stream>>>(
        x, conv_w, conv_b, bn_g, bn_b, bn_m, bn_v, h0);

    // layer-0 input projections (K=32), fwd+bwd in one launch (1D swizzled)
    gemm_mfma<<<4096, 256, 0, stream>>>(
        h0, wpk, wpk + 32768, nullptr, b0f, b0b, nullptr, xgf, xgb, nullptr,
        32768, 1024, 32);

    lstm_reg<<<128, 1024, 0, stream>>>(xgf, xgb, wl0, out0);

    // layer-1 input projections (K=512)
    gemm_mfma<<<4096, 256, 0, stream>>>(
        out0, wpk + 65536, wpk + 589824, nullptr, b1f, b1b, nullptr,
        xgf, xgb, nullptr, 32768, 1024, 512);

    lstm_reg<<<128, 1024, 0, stream>>>(xgf, xgb, wl1, out1);

    // QKV projections (N=512), 3-way
    gemm_mfma<<<3072, 256, 0, stream>>>(
        out1, wpk + 1114112, wpk + 1376256, wpk + 1638400, bq, bk, bv,
        qb, kb, vb, 32768, 512, 512);

    vt_transpose<<<dim3(8, 8, 64), 256, 0, stream>>>(vb, vtb);

    attention_mfma<<<1024, 256, 0, stream>>>(qb, kb, vtb, out1);

    ln_pool_fc<<<dim3(64, 64), 512, 0, stream>>>(out1, ln_g, ln_b, fc_w, fc_b, out);
}

// Round 10
// 2719.408 us; speedup vs baseline: 1.1579x; 1.1579x over previous
//
#include <hip/hip_runtime.h>
#include <hip/hip_bf16.h>
#include <math.h>

#define L_IN 1549
#define S_OUT 512

typedef __hip_bfloat16 bf16;
typedef __attribute__((ext_vector_type(8))) short bfrag;    // 8 bf16 (4 VGPRs)
typedef __attribute__((ext_vector_type(4))) float f32x4;    // MFMA accumulator

__device__ __forceinline__ float bfbits2f(unsigned short u) {
    union { unsigned int i; float f; } x;
    x.i = ((unsigned int)u) << 16;
    return x.f;
}
__device__ __forceinline__ unsigned short f2bfbits(float f) {
    union { float f; unsigned int i; } x; x.f = f;
    unsigned int lsb = (x.i >> 16) & 1;
    return (unsigned short)((x.i + 0x7fff + lsb) >> 16);
}

// fast activations: single v_exp_f32 / v_rcp_f32 (<=1 ulp HW ops).
__device__ __forceinline__ float fast_sig(float x) {
    float e = __builtin_amdgcn_exp2f(-1.442695041f * x);   // exp(-x)
    return __builtin_amdgcn_rcpf(1.f + e);
}
__device__ __forceinline__ float fast_tanh(float x) {
    float e = __builtin_amdgcn_exp2f(2.885390082f * x);    // exp(2x)
    return 1.f - 2.f * __builtin_amdgcn_rcpf(1.f + e);
}

// bf16-pair dot product: c + lo(w)*lo(h) + hi(w)*hi(h)
#if __has_builtin(__builtin_amdgcn_fdot2_f32_bf16)
typedef __attribute__((ext_vector_type(2))) __bf16 v2bf;
__device__ __forceinline__ float dot2bf(unsigned int w, unsigned int h, float c) {
    union { unsigned int u; v2bf v; } a, b;
    a.u = w; b.u = h;
    return __builtin_amdgcn_fdot2_f32_bf16(a.v, b.v, c, false);
}
#else
__device__ __forceinline__ float dot2bf(unsigned int w, unsigned int h, float c) {
    union { unsigned int i; float f; } w0, w1, h0, h1;
    w0.i = w << 16; w1.i = w & 0xffff0000u;
    h0.i = h << 16; h1.i = h & 0xffff0000u;
    return c + w0.f * h0.f + w1.f * h1.f;
}
#endif

// ---------------------------------------------------------------------------
// conv1d(k=16,pad=1) + BN + ReLU + maxpool(3,3) + transpose -> h0 (B,512,32) bf16
// ---------------------------------------------------------------------------
__global__ __launch_bounds__(256) void conv_bn_pool(
    const float* __restrict__ x, const float* __restrict__ w,
    const float* __restrict__ cb, const float* __restrict__ gamma,
    const float* __restrict__ beta, const float* __restrict__ mean,
    const float* __restrict__ var, bf16* __restrict__ h0)
{
    int b  = blockIdx.y;
    int sg = blockIdx.x;
    __shared__ float xs[32][40];
    int tid = threadIdx.x;
    int base = sg * 24;
    for (int i = tid; i < 32 * 40; i += 256) {
        int ci = i / 40, dl = i % 40;
        int l = base - 1 + dl;
        xs[ci][dl] = (l >= 0 && l < L_IN) ? x[(size_t)(b * 32 + ci) * L_IN + l] : 0.f;
    }
    __syncthreads();
    int c = tid & 31, sl = tid >> 5;
    float scale = gamma[c] * rsqrtf(var[c] + 1e-5f);
    float shift = beta[c] - mean[c] * scale;
    float bias = cb[c];
    float acc0 = bias, acc1 = bias, acc2 = bias;
    int off0 = 3 * sl;
    for (int ci = 0; ci < 32; ++ci) {
        const float* wrp = w + (size_t)(c * 32 + ci) * 16;
        float4 w0 = *(const float4*)(wrp);
        float4 w1 = *(const float4*)(wrp + 4);
        float4 w2 = *(const float4*)(wrp + 8);
        float4 w3 = *(const float4*)(wrp + 12);
        float wk[16] = {w0.x, w0.y, w0.z, w0.w, w1.x, w1.y, w1.z, w1.w,
                        w2.x, w2.y, w2.z, w2.w, w3.x, w3.y, w3.z, w3.w};
        const float* xr = &xs[ci][off0];
        #pragma unroll
        for (int kk = 0; kk < 16; ++kk) {
            float xv0 = xr[kk];
            float xv1 = xr[kk + 1];
            float xv2 = xr[kk + 2];
            acc0 += xv0 * wk[kk];
            acc1 += xv1 * wk[kk];
            acc2 += xv2 * wk[kk];
        }
    }
    float y0 = fmaxf(acc0 * scale + shift, 0.f);
    float y1 = fmaxf(acc1 * scale + shift, 0.f);
    float y2 = fmaxf(acc2 * scale + shift, 0.f);
    float best = fmaxf(fmaxf(y0, y1), y2);
    int s = sg * 8 + sl;
    h0[((size_t)b * S_OUT + s) * 32 + c] = __float2bfloat16(best);
}

// ---------------------------------------------------------------------------
// Pack 4 x W_hh (1024,256) fp32 for lstm_reg (k-split layout, blockIdx.y=set).
// Consumer thread t (0..511): khalf = t>>8, owns gates 4*(t&255)+gi (gi 0..3)
// for k-pairs kp = khalf*64 + kpl (kpl 0..63).
//  R (reg,   kpl  0..49): out[kpl*2048 + 4t + gi]            (102400)
//  L (LDS,   kpl 50..56): out[102400 + (kpl-50)*2048 + 4t+gi] (14336)
//  S (stream,kpl 57..63): out[116736 + (kpl-57)*2048 + 4t+gi] (14336)
// value = pack(W[g*256 + 2kp], W[g*256 + 2kp + 1])
// ---------------------------------------------------------------------------
__global__ void pack_lstm4(
    const float* __restrict__ W0, const float* __restrict__ W1,
    const float* __restrict__ W2, const float* __restrict__ W3,
    unsigned int* __restrict__ outbase)
{
    int set = blockIdx.y;
    const float* W = (set == 0) ? W0 : (set == 1) ? W1 : (set == 2) ? W2 : W3;
    unsigned int* out = outbase + (size_t)set * 131072;
    int i = blockIdx.x * 256 + threadIdx.x;   // 0..131071
    int kpl, j;
    if (i < 102400) {
        kpl = i >> 11; j = i & 2047;
    } else if (i < 116736) {
        int m = i - 102400;
        kpl = 50 + (m >> 11); j = m & 2047;
    } else {
        int m = i - 116736;
        kpl = 57 + (m >> 11); j = m & 2047;
    }
    int t = j >> 2, gi = j & 3;
    int g = 4 * (t & 255) + gi;
    int kp = (t >> 8) * 64 + kpl;
    unsigned int lo = f2bfbits(W[(size_t)g * 256 + 2 * kp]);
    unsigned int hi = f2bfbits(W[(size_t)g * 256 + 2 * kp + 1]);
    out[i] = lo | (hi << 16);
}

// ---------------------------------------------------------------------------
// Pack the 7 GEMM B matrices (fp32 -> bf16, RNE) ONCE.
// ---------------------------------------------------------------------------
__global__ __launch_bounds__(256) void pack_b7(
    const float* __restrict__ A0, const float* __restrict__ A1,
    const float* __restrict__ A2, const float* __restrict__ A3,
    const float* __restrict__ A4, const float* __restrict__ A5,
    const float* __restrict__ A6, unsigned short* __restrict__ out)
{
    int i = blockIdx.x * 256 + threadIdx.x;
    const float* src; int j;
    if      (i <   32768) { src = A0; j = i; }
    else if (i <   65536) { src = A1; j = i - 32768; }
    else if (i <  589824) { src = A2; j = i - 65536; }
    else if (i < 1114112) { src = A3; j = i - 589824; }
    else if (i < 1376256) { src = A4; j = i - 1114112; }
    else if (i < 1638400) { src = A5; j = i - 1376256; }
    else if (i < 1900544) { src = A6; j = i - 1638400; }
    else return;
    out[i] = f2bfbits(src[j]);
}

// ---------------------------------------------------------------------------
// MFMA bf16 GEMM:  C = A @ B^T + bias.  A (M,K) bf16, B (N,K) bf16.
// 128x128 tile, BK=32, LDS stride 40 (conflict-free), XCD-aware swizzle.
// ---------------------------------------------------------------------------
#define LDA 40
__global__ __launch_bounds__(256) void gemm_mfma(
    const bf16* __restrict__ A,
    const bf16* __restrict__ Bm0, const bf16* __restrict__ Bm1, const bf16* __restrict__ Bm2,
    const float* __restrict__ bs0, const float* __restrict__ bs1, const float* __restrict__ bs2,
    bf16* __restrict__ Cm0, bf16* __restrict__ Cm1, bf16* __restrict__ Cm2,
    int M, int N, int K)
{
    int nbn = N >> 7;                    // N/128
    int nbm = M >> 7;                    // M/128
    int lid = blockIdx.x;
    int xcd = lid & 7;
    int slot = lid >> 3;
    int bn = slot % nbn;
    int pair = xcd + 8 * (slot / nbn);   // (bm, z) pair index
    int bm = pair % nbm;
    int z  = pair / nbm;

    const bf16* B = (z == 0) ? Bm0 : ((z == 1) ? Bm1 : Bm2);
    const float* bias = (z == 0) ? bs0 : ((z == 1) ? bs1 : bs2);
    bf16* C = (z == 0) ? Cm0 : ((z == 1) ? Cm1 : Cm2);

    __shared__ bf16 As[128 * LDA];
    __shared__ bf16 Bs[128 * LDA];

    int tid = threadIdx.x;
    int lane = tid & 63;
    int wave = tid >> 6;
    int wm = (wave >> 1) * 64;
    int wn = (wave & 1) * 64;

    int sr = tid >> 2;
    int sc = (tid & 3) * 8;
    const bf16* Ag = A + (size_t)(bm * 128 + sr) * K + sc;
    const bf16* Bg = B + (size_t)(bn * 128 + sr) * K + sc;

    int fm = lane & 15;
    int fk = (lane >> 4) * 8;

    f32x4 acc[4][4];
    #pragma unroll
    for (int i = 0; i < 4; ++i)
        #pragma unroll
        for (int j = 0; j < 4; ++j) acc[i][j] = (f32x4)(0.f);

    for (int k0 = 0; k0 < K; k0 += 32) {
        float4 a0 = *(const float4*)(Ag + k0);
        float4 a1 = *(const float4*)(Ag + (size_t)64 * K + k0);
        float4 b0 = *(const float4*)(Bg + k0);
        float4 b1 = *(const float4*)(Bg + (size_t)64 * K + k0);
        __syncthreads();
        *(float4*)(As + sr * LDA + sc)        = a0;
        *(float4*)(As + (sr + 64) * LDA + sc) = a1;
        *(float4*)(Bs + sr * LDA + sc)        = b0;
        *(float4*)(Bs + (sr + 64) * LDA + sc) = b1;
        __syncthreads();

        bfrag af[4], bfr[4];
        #pragma unroll
        for (int i = 0; i < 4; ++i)
            af[i] = *(const bfrag*)(As + (wm + i * 16 + fm) * LDA + fk);
        #pragma unroll
        for (int j = 0; j < 4; ++j)
            bfr[j] = *(const bfrag*)(Bs + (wn + j * 16 + fm) * LDA + fk);
        #pragma unroll
        for (int i = 0; i < 4; ++i)
            #pragma unroll
            for (int j = 0; j < 4; ++j)
                acc[i][j] = __builtin_amdgcn_mfma_f32_16x16x32_bf16(
                    af[i], bfr[j], acc[i][j], 0, 0, 0);
    }

    int rbase = (lane >> 4) * 4;
    #pragma unroll
    for (int j = 0; j < 4; ++j) {
        int n = bn * 128 + wn + j * 16 + (lane & 15);
        float bv = bias[n];
        #pragma unroll
        for (int i = 0; i < 4; ++i) {
            #pragma unroll
            for (int r = 0; r < 4; ++r) {
                int m = bm * 128 + wm + i * 16 + rbase + r;
                C[(size_t)m * N + n] = __float2bfloat16(acc[i][j][r] + bv);
            }
        }
    }
}

// ---------------------------------------------------------------------------
// LSTM recurrence, k-split variant (512 thr).
// R9 measured broadcast ds_read_b128 at ~4 cyc pipe occupancy: the 512-thr
// kernel's 256 h-broadcast reads + 112 lw b64 reads/step/CU make the LDS
// pipe a co-bottleneck with VALU.  K-SPLIT: thread t (khalf = t>>8) owns
// 4 gates (4*(t&255)+gi) x 64 kp -> per-wave h reads 32->16 b128, lw reads
// 14 b64 -> 7 b128.  VALU issue unchanged (256 dot2/thread, 4 indep chains).
// Partials combined through the existing gsh exchange (gsh[2][1024]); the
// activation (t<256) sums two halves.  xg added by khalf=0 threads (uint2,
// 4 consecutive gates).  2 barriers/step; out store post-barrier.
// ---------------------------------------------------------------------------
__global__ __launch_bounds__(512, 2) void lstm_reg(
    const bf16* __restrict__ xg_f, const bf16* __restrict__ xg_b,
    const unsigned int* __restrict__ Wl, bf16* __restrict__ out)
{
    int u = blockIdx.x;          // 0..127
    int b = u & 63, dir = u >> 6;
    const unsigned int* W = Wl + (size_t)dir * 131072;
    const bf16* xg = dir ? xg_b : xg_f;
    int t = threadIdx.x;         // 0..511

    __shared__ unsigned int lw[14336];                    // 56 KB weight slice
    __shared__ __align__(16) unsigned int hsb[2][128];    // h bf16 pairs, dbuf
    __shared__ __align__(16) float gsh[2][1024];          // partial gates

    unsigned int wr[200];        // kpl 0..49, 4 gates each
    #pragma unroll
    for (int j = 0; j < 50; ++j)
        *(uint4*)&wr[j * 4] = *(const uint4*)&W[j * 2048 + 4 * t];
    for (int i = t; i < 14336; i += 512) lw[i] = W[102400 + i];
    if (t < 128) { hsb[0][t] = 0u; }
    float cst = 0.f;             // cell state of position t (t < 256)
    __syncthreads();

    const unsigned int* Wst = W + 116736;
    int par = 0;
    int khalf = t >> 8;          // 0 or 1
    int gq = t & 255;            // gate quad: gates 4gq..4gq+3
    const unsigned int* lwp = lw + 4 * t;
    unsigned short hb = 0;
    size_t oaddr = 0;

    for (int step = 0; step < 512; ++step) {
        int ts = dir ? (511 - step) : step;

        // streamed weights (7 x uint4) + xg (khalf0 only): issued first
        uint4 sv[7];
        #pragma unroll
        for (int s = 0; s < 7; ++s)
            sv[s] = *(const uint4*)&Wst[s * 2048 + 4 * t];
        uint2 xv = make_uint2(0u, 0u);
        if (khalf == 0)
            xv = *(const uint2*)(xg + ((size_t)b * 512 + ts) * 1024 + 4 * t);

        const unsigned int* hs = hsb[par] + khalf * 64;
        float a0 = 0.f, a1 = 0.f, a2 = 0.f, a3 = 0.f;
        #pragma unroll
        for (int q = 0; q < 16; ++q) {
            uint4 hv = *(const uint4*)&hs[q * 4];
            #pragma unroll
            for (int r = 0; r < 4; ++r) {
                int kpl = q * 4 + r;
                unsigned int h2 = (&hv.x)[r];
                if (kpl < 50) {
                    const unsigned int* w4 = &wr[kpl * 4];
                    a0 = dot2bf(w4[0], h2, a0);
                    a1 = dot2bf(w4[1], h2, a1);
                    a2 = dot2bf(w4[2], h2, a2);
                    a3 = dot2bf(w4[3], h2, a3);
                } else if (kpl < 57) {
                    uint4 wv = *(const uint4*)&lwp[(kpl - 50) * 2048];
                    a0 = dot2bf(wv.x, h2, a0);
                    a1 = dot2bf(wv.y, h2, a1);
                    a2 = dot2bf(wv.z, h2, a2);
                    a3 = dot2bf(wv.w, h2, a3);
                } else {
                    uint4 wv = sv[kpl - 57];
                    a0 = dot2bf(wv.x, h2, a0);
                    a1 = dot2bf(wv.y, h2, a1);
                    a2 = dot2bf(wv.z, h2, a2);
                    a3 = dot2bf(wv.w, h2, a3);
                }
            }
        }
        if (khalf == 0) {
            a0 += bfbits2f((unsigned short)(xv.x & 0xffff));
            a1 += bfbits2f((unsigned short)(xv.x >> 16));
            a2 += bfbits2f((unsigned short)(xv.y & 0xffff));
            a3 += bfbits2f((unsigned short)(xv.y >> 16));
        }

        *(float4*)&gsh[khalf][4 * gq] = make_float4(a0, a1, a2, a3);
        __syncthreads();

        bool act = (t < 256);
        if (act) {
            float gi = gsh[0][t]       + gsh[1][t];
            float gf = gsh[0][256 + t] + gsh[1][256 + t];
            float gg = gsh[0][512 + t] + gsh[1][512 + t];
            float go = gsh[0][768 + t] + gsh[1][768 + t];
            float si = fast_sig(gi);
            float sf = fast_sig(gf);
            float so = fast_sig(go);
            cst = sf * cst + si * fast_tanh(gg);
            float h = so * fast_tanh(cst);
            hb = f2bfbits(h);
            ((unsigned short*)hsb[par ^ 1])[t] = hb;
            oaddr = ((size_t)b * 512 + ts) * 512 + dir * 256 + t;
        }
        __syncthreads();
        // out store off the critical path: drains at the NEXT step's barrier
        if (act) *(unsigned short*)(out + oaddr) = hb;
        par ^= 1;
    }
}

// ---------------------------------------------------------------------------
// V transpose: vt[b][n][s] = v[b][s][n]   (64x64 tiles via LDS)
// ---------------------------------------------------------------------------
__global__ __launch_bounds__(256) void vt_transpose(
    const bf16* __restrict__ v, bf16* __restrict__ vt)
{
    __shared__ unsigned short tile[64 * 73];
    int b = blockIdx.z;
    int s0 = blockIdx.x * 64, n0 = blockIdx.y * 64;
    int tid = threadIdx.x;
    #pragma unroll
    for (int u = 0; u < 2; ++u) {
        int idx = tid + u * 256;
        int si = idx >> 3, nj = (idx & 7) << 3;
        bfrag val = *(const bfrag*)(v + ((size_t)(b * 512 + s0 + si)) * 512 + n0 + nj);
        #pragma unroll
        for (int jj = 0; jj < 8; ++jj)
            tile[(nj + jj) * 73 + si] = ((unsigned short*)&val)[jj];
    }
    __syncthreads();
    #pragma unroll
    for (int u = 0; u < 2; ++u) {
        int idx = tid + u * 256;
        int ni = idx >> 3, sj = (idx & 7) << 3;
        unsigned short outv[8];
        #pragma unroll
        for (int jj = 0; jj < 8; ++jj)
            outv[jj] = tile[ni * 73 + sj + jj];
        *(float4*)(vt + (size_t)b * 262144 + (size_t)(n0 + ni) * 512 + s0 + sj) =
            *(float4*)outv;
    }
}

// ---------------------------------------------------------------------------
// MFMA attention (fast exp2/log2 head-softmax).
// XCD-aware block swizzle: all 16 s0-tiles of one batch land on the SAME XCD.
// ---------------------------------------------------------------------------
__global__ __launch_bounds__(256, 2) void attention_mfma(
    const bf16* __restrict__ q, const bf16* __restrict__ k,
    const bf16* __restrict__ vt, bf16* r)
{
    int n_ = blockIdx.x;                 // 0..1023
    int xcd = n_ & 7;
    int slot = n_ >> 3;                  // 0..127 within XCD
    int b = xcd + ((slot >> 4) << 3);    // batches b = xcd (mod 8) on this XCD
    int s0 = (slot & 15) * 32;
    int tid = threadIdx.x;
    int wave = tid >> 6;
    int sw = wave & 1, dh = wave >> 1;
    int lane = tid & 63;
    int L15 = lane & 15, quad = lane >> 4;

    const bf16* qrow = q + ((size_t)(b * 512 + s0 + sw * 16 + L15)) * 512;
    bfrag qf[8][2];
    #pragma unroll
    for (int h = 0; h < 8; ++h) {
        qf[h][0] = *(const bfrag*)(qrow + h * 64 + quad * 8);
        qf[h][1] = *(const bfrag*)(qrow + h * 64 + 32 + quad * 8);
    }

    f32x4 ctxa[8][2];
    #pragma unroll
    for (int h = 0; h < 8; ++h) {
        ctxa[h][0] = (f32x4)(0.f);
        ctxa[h][1] = (f32x4)(0.f);
    }

    int tperm = ((L15 >> 2) << 3) + (L15 & 3);
    const bf16* kbase = k + (size_t)(b * 512) * 512;
    const bf16* vbase = vt + (size_t)b * 262144;

    for (int tc = 0; tc < 512; tc += 32) {
        f32x4 sa[8][2];
        #pragma unroll
        for (int h = 0; h < 8; ++h) {
            #pragma unroll
            for (int tile = 0; tile < 2; ++tile) {
                const bf16* krow = kbase
                    + (size_t)(tc + tile * 4 + tperm) * 512 + h * 64 + quad * 8;
                bfrag a0 = *(const bfrag*)(krow);
                bfrag a1 = *(const bfrag*)(krow + 32);
                f32x4 acc = __builtin_amdgcn_mfma_f32_16x16x32_bf16(
                    a0, qf[h][0], (f32x4)(0.f), 0, 0, 0);
                acc = __builtin_amdgcn_mfma_f32_16x16x32_bf16(
                    a1, qf[h][1], acc, 0, 0, 0);
                sa[h][tile] = acc;
            }
        }
        bfrag pf[8];
        #pragma unroll
        for (int tile = 0; tile < 2; ++tile) {
            #pragma unroll
            for (int rr = 0; rr < 4; ++rr) {
                float sc[8];
                float m = -1e30f;
                #pragma unroll
                for (int h = 0; h < 8; ++h) {
                    sc[h] = sa[h][tile][rr] * 0.125f;
                    m = fmaxf(m, sc[h]);
                }
                float sum = 0.f;
                #pragma unroll
                for (int h = 0; h < 8; ++h)
                    sum += __builtin_amdgcn_exp2f((sc[h] - m) * 1.442695041f);
                float lse = m + 0.6931471806f * __builtin_amdgcn_logf(sum);
                #pragma unroll
                for (int h = 0; h < 8; ++h)
                    ((unsigned short*)&pf[h])[tile * 4 + rr] = f2bfbits(sc[h] - lse);
            }
        }
        #pragma unroll
        for (int h = 0; h < 8; ++h) {
            #pragma unroll
            for (int dt = 0; dt < 2; ++dt) {
                int n = h * 64 + dh * 32 + dt * 16 + L15;
                bfrag vf = *(const bfrag*)(vbase + (size_t)n * 512 + tc + quad * 8);
                ctxa[h][dt] = __builtin_amdgcn_mfma_f32_16x16x32_bf16(
                    pf[h], vf, ctxa[h][dt], 0, 0, 0);
            }
        }
    }
    #pragma unroll
    for (int h = 0; h < 8; ++h) {
        #pragma unroll
        for (int dt = 0; dt < 2; ++dt) {
            int n = h * 64 + dh * 32 + dt * 16 + L15;
            #pragma unroll
            for (int rr = 0; rr < 4; ++rr) {
                size_t addr =
                    ((size_t)(b * 512 + s0 + sw * 16 + quad * 4 + rr)) * 512 + n;
                float o = __bfloat162float(r[addr]);
                r[addr] = __float2bfloat16(o + ctxa[h][dt][rr]);
            }
        }
    }
}

// ---------------------------------------------------------------------------
// LayerNorm(last dim) -> mean over S -> fc, barrier-free (one wave per row).
// ---------------------------------------------------------------------------
__global__ __launch_bounds__(512) void ln_pool_fc(
    const bf16* __restrict__ r, const float* __restrict__ g, const float* __restrict__ bt,
    const float* __restrict__ fcw, const float* __restrict__ fcb, float* __restrict__ out)
{
    int b = blockIdx.y;
    int s = blockIdx.x * 8 + (threadIdx.x >> 6);
    int lane = threadIdx.x & 63;
    int n0 = lane * 8;

    float gf[8];
    float btf = 0.f;
    #pragma unroll
    for (int j = 0; j < 8; ++j) {
        float fw = fcw[n0 + j];
        gf[j] = g[n0 + j] * fw;
        btf += bt[n0 + j] * fw;
    }

    bfrag rv = *(const bfrag*)(r + ((size_t)(b * 512 + s)) * 512 + n0);
    float v[8];
    float s1 = 0.f, s2 = 0.f;
    #pragma unroll
    for (int j = 0; j < 8; ++j) {
        v[j] = bfbits2f(((const unsigned short*)&rv)[j]);
        s1 += v[j];
        s2 += v[j] * v[j];
    }
    #pragma unroll
    for (int off = 32; off > 0; off >>= 1) {
        s1 += __shfl_xor(s1, off);
        s2 += __shfl_xor(s2, off);
    }
    float mu = s1 * (1.f / 512.f);
    float var = s2 * (1.f / 512.f) - mu * mu;
    float rs = rsqrtf(var + 1e-5f);

    float d = 0.f;
    #pragma unroll
    for (int j = 0; j < 8; ++j) d += (v[j] - mu) * gf[j];
    #pragma unroll
    for (int off = 32; off > 0; off >>= 1) {
        d += __shfl_down(d, off);
        btf += __shfl_down(btf, off);
    }
    if (lane == 0) {
        float val = d * rs * (1.f / 512.f);
        if (s == 0) val += btf + fcb[0];
        atomicAdd(out + b, val);
    }
}

// ---------------------------------------------------------------------------
// Workspace layout (< 200 MiB):
//   [0,64M)        xgf bf16            -> later q,k
//   [64,128M)      xgb bf16            -> later v
//   [128,160M)     out0 bf16           -> later vt (V transposed)
//   [160,192M)     out1 bf16 (attention in-place)
//   [192,194M)     h0 bf16
//   [194,196M)     wl0/wl1 (4 contiguous sets x 131,072 dwords)
//   [196,~199.6M)  wpk bf16 (7 packed B matrices, 1,900,544 elems)
// ---------------------------------------------------------------------------
extern "C" void kernel_launch(void* const* d_in, const int* in_sizes, int n_in,
                              void* d_out, int out_size, void* d_ws, size_t ws_size,
                              hipStream_t stream)
{
    (void)in_sizes; (void)n_in; (void)ws_size;
    const float* x      = (const float*)d_in[0];
    const float* conv_w = (const float*)d_in[1];
    const float* conv_b = (const float*)d_in[2];
    const float* bn_g   = (const float*)d_in[3];
    const float* bn_b   = (const float*)d_in[4];
    const float* bn_m   = (const float*)d_in[5];
    const float* bn_v   = (const float*)d_in[6];
    const float* W_ih0f = (const float*)d_in[7];
    const float* W_hh0f = (const float*)d_in[8];
    const float* b0f    = (const float*)d_in[9];
    const float* W_ih0b = (const float*)d_in[10];
    const float* W_hh0b = (const float*)d_in[11];
    const float* b0b    = (const float*)d_in[12];
    const float* W_ih1f = (const float*)d_in[13];
    const float* W_hh1f = (const float*)d_in[14];
    const float* b1f    = (const float*)d_in[15];
    const float* W_ih1b = (const float*)d_in[16];
    const float* W_hh1b = (const float*)d_in[17];
    const float* b1b    = (const float*)d_in[18];
    const float* Wq = (const float*)d_in[19];
    const float* bq = (const float*)d_in[20];
    const float* Wk = (const float*)d_in[21];
    const float* bk = (const float*)d_in[22];
    const float* Wv = (const float*)d_in[23];
    const float* bv = (const float*)d_in[24];
    const float* ln_g = (const float*)d_in[25];
    const float* ln_b = (const float*)d_in[26];
    const float* fc_w = (const float*)d_in[27];
    const float* fc_b = (const float*)d_in[28];
    float* out = (float*)d_out;

    char* ws = (char*)d_ws;
    bf16* xgf  = (bf16*)ws;                               // 33,554,432
    bf16* xgb  = xgf + 33554432;                          // 33,554,432
    bf16* out0 = (bf16*)(ws + 134217728);                 // 16,777,216
    bf16* out1 = (bf16*)(ws + 167772160);                 // 16,777,216
    bf16* h0   = (bf16*)(ws + 201326592);                 // 1,048,576
    unsigned int* wl0 = (unsigned int*)(ws + 203423744);  // 262,144 dwords
    unsigned int* wl1 = wl0 + 262144;                     // 262,144 dwords
    bf16* wpk  = (bf16*)(ws + 205520896);                 // 1,900,544 bf16
    // q,k,v alias the (dead after lstm1) xg region; vt aliases dead out0
    bf16* qb = xgf;
    bf16* kb = xgf + 16777216;
    bf16* vb = xgb;
    bf16* vtb = out0;

    hipMemsetAsync(d_out, 0, (size_t)out_size * sizeof(float), stream);

    pack_lstm4<<<dim3(512, 4), 256, 0, stream>>>(
        W_hh0f, W_hh0b, W_hh1f, W_hh1b, wl0);

    pack_b7<<<7424, 256, 0, stream>>>(
        W_ih0f, W_ih0b, W_ih1f, W_ih1b, Wq, Wk, Wv, (unsigned short*)wpk);

    conv_bn_pool<<<dim3(64, 64), 256, 0, stream>>>(
        x, conv_w, conv_b, bn_g, bn_b, bn_m, bn_v, h0);

    // layer-0 input projections (K=32), fwd+bwd in one launch (1D swizzled)
    gemm_mfma<<<4096, 256, 0, stream>>>(
        h0, wpk, wpk + 32768, nullptr, b0f, b0b, nullptr, xgf, xgb, nullptr,
        32768, 1024, 32);

    lstm_reg<<<128, 512, 0, stream>>>(xgf, xgb, wl0, out0);

    // layer-1 input projections (K=512)
    gemm_mfma<<<4096, 256, 0, stream>>>(
        out0, wpk + 65536, wpk + 589824, nullptr, b1f, b1b, nullptr,
        xgf, xgb, nullptr, 32768, 1024, 512);

    lstm_reg<<<128, 512, 0, stream>>>(xgf, xgb, wl1, out1);

    // QKV projections (N=512), 3-way
    gemm_mfma<<<3072, 256, 0, stream>>>(
        out1, wpk + 1114112, wpk + 1376256, wpk + 1638400, bq, bk, bv,
        qb, kb, vb, 32768, 512, 512);

    vt_transpose<<<dim3(8, 8, 64), 256, 0, stream>>>(vb, vtb);

    attention_mfma<<<1024, 256, 0, stream>>>(qb, kb, vtb, out1);

    ln_pool_fc<<<dim3(64, 64), 512, 0, stream>>>(out1, ln_g, ln_b, fc_w, fc_b, out);
}